// Round 18
// baseline (68.137 us; speedup 1.0000x reference)
//
#include <hip/hip_runtime.h>
#include <hip/hip_bf16.h>

#define D_ 256
#define H_ 8
#define B_ 2
#define S_ 2048
#define MTOT 4096
#define AUGQ 64          // q(32) + pq(16) + [maskbias](1) + pad(15)
#define NBH 16           // B_*H_
#define KPAD 72
#define NSPLIT 8
#define NJ 4             // key tiles (of 64) per split
#define LOG2E 1.4426950408889634f

typedef __attribute__((ext_vector_type(8))) short short8;
typedef __attribute__((ext_vector_type(4))) short short4v;
typedef __attribute__((ext_vector_type(4))) float f32x4;

static __device__ __forceinline__ short bf16_of(float f) {
  union { __hip_bfloat16 h; short s; } u;
  u.h = __float2bfloat16(f);
  return u.s;
}
static __device__ __forceinline__ float f_of_bf16(short s) {
  union { float f; unsigned int u; } u;
  u.u = ((unsigned int)(unsigned short)s) << 16;
  return u.f;
}

// key permutation within a 64-key tile: V column c holds key sinv(c)
static __device__ __forceinline__ int sinv64(int c) {
  return (((((c >> 2) & 1) << 1) | ((c >> 5) & 1)) << 4) + (((c >> 3) & 3) << 2) + (c & 3);
}

// ---------------- prep: sectioned by blockIdx (R17 layout) ----------------

__global__ __launch_bounds__(256) void prep_all(
    const float* __restrict__ Wq, const float* __restrict__ Wk,
    const float* __restrict__ Wv, const float* __restrict__ Wo,
    const float* __restrict__ X, const float* __restrict__ coords,
    const int* __restrict__ mask,
    const float* __restrict__ Wpq, const float* __restrict__ bpq,
    const float* __restrict__ Wpk, const float* __restrict__ bpk,
    short* __restrict__ Wqkv_t, short* __restrict__ Wo_t,
    short* __restrict__ Xb,
    short* __restrict__ Qa, short* __restrict__ Ka, short* __restrict__ VaT) {
  int bid = blockIdx.x, tid = threadIdx.x;

  if (bid < 64) {
    __shared__ short T[64][72];
    const float* src;
    short* dst;
    int k0, n0g;
    if (bid < 48) {
      int nt = bid >> 2;
      k0 = (bid & 3) * 64;
      n0g = nt * 64;
      src = (n0g < 256) ? Wq : (n0g < 512 ? Wk : Wv);
      dst = Wqkv_t;
    } else {
      int t2 = bid - 48;
      k0 = (t2 & 3) * 64;
      n0g = (t2 >> 2) * 64;
      src = Wo;
      dst = Wo_t;
    }
    int ncol = n0g & 255;
    int rr = tid >> 4, cc = (tid & 15) * 4;
#pragma unroll
    for (int i = 0; i < 4; i++) {
      int r = rr + i * 16;
      f32x4 v = *reinterpret_cast<const f32x4*>(&src[(size_t)(k0 + r) * 256 + ncol + cc]);
      T[cc + 0][r] = bf16_of(v[0]);
      T[cc + 1][r] = bf16_of(v[1]);
      T[cc + 2][r] = bf16_of(v[2]);
      T[cc + 3][r] = bf16_of(v[3]);
    }
    __syncthreads();
    int n = tid >> 2, kk = (tid & 3) * 16;
    *reinterpret_cast<short8*>(&dst[(size_t)(n0g + n) * 256 + k0 + kk]) =
        *reinterpret_cast<const short8*>(&T[n][kk]);
    *reinterpret_cast<short8*>(&dst[(size_t)(n0g + n) * 256 + k0 + kk + 8]) =
        *reinterpret_cast<const short8*>(&T[n][kk + 8]);
    return;
  }

  if (bid < 576) {
    size_t i = (size_t)(bid - 64) * 2048 + tid * 8;
    f32x4 v0 = *reinterpret_cast<const f32x4*>(&X[i]);
    f32x4 v1 = *reinterpret_cast<const f32x4*>(&X[i + 4]);
    short8 o;
    o[0] = bf16_of(v0[0]); o[1] = bf16_of(v0[1]); o[2] = bf16_of(v0[2]); o[3] = bf16_of(v0[3]);
    o[4] = bf16_of(v1[0]); o[5] = bf16_of(v1[1]); o[6] = bf16_of(v1[2]); o[7] = bf16_of(v1[3]);
    *reinterpret_cast<short8*>(&Xb[i]) = o;
    return;
  }

  if (bid < 704) {
    __shared__ float cx[32], cy[32], cz[32];
    int m0 = (bid - 576) * 32;
    if (tid < 32)       cx[tid]      = coords[(size_t)(m0 + tid) * 9 + 3];
    else if (tid < 64)  cy[tid - 32] = coords[(size_t)(m0 + tid - 32) * 9 + 4];
    else if (tid < 96)  cz[tid - 64] = coords[(size_t)(m0 + tid - 64) * 9 + 5];
    __syncthreads();
    int m_l = tid >> 3, h = tid & 7;
    int m = m0 + m_l;
    int b = m >> 11, s = m & 2047;
    float r0 = cx[m_l], r1 = cy[m_l], r2 = cz[m_l];
    size_t base = ((size_t)(b * 8 + h) * S_ + s) * AUGQ;
    short8 pqv[2], pkv[2];
#pragma unroll
    for (int c = 0; c < 2; c++)
#pragma unroll
      for (int i = 0; i < 8; i++) {
        int j = h * 16 + c * 8 + i;
        float pq = r0 * Wpq[j] + r1 * Wpq[128 + j] + r2 * Wpq[256 + j] + bpq[j];
        float pk = r0 * Wpk[j] + r1 * Wpk[128 + j] + r2 * Wpk[256 + j] + bpk[j];
        pqv[c][i] = bf16_of(pq * LOG2E);
        pkv[c][i] = bf16_of(pk * 0.25f);
      }
    short8 padq = {};
    padq[0] = bf16_of(LOG2E);
    short8 padk = {};
    padk[0] = mask[m] ? (short)0 : bf16_of(-1e9f);
    short8 z = {};
    *reinterpret_cast<short8*>(&Qa[base + 32]) = pqv[0];
    *reinterpret_cast<short8*>(&Qa[base + 40]) = pqv[1];
    *reinterpret_cast<short8*>(&Qa[base + 48]) = padq;
    *reinterpret_cast<short8*>(&Qa[base + 56]) = z;
    *reinterpret_cast<short8*>(&Ka[base + 32]) = pkv[0];
    *reinterpret_cast<short8*>(&Ka[base + 40]) = pkv[1];
    *reinterpret_cast<short8*>(&Ka[base + 48]) = padk;
    *reinterpret_cast<short8*>(&Ka[base + 56]) = z;
    return;
  }

  {
    __shared__ float gx[256], gy[256], gz[256];
    __shared__ float wco[4][16];
    int bid2 = bid - 704;
    int bh = bid2 >> 3, chunk = bid2 & 7;
    int b = bh >> 3, h = bh & 7;
    int s0 = chunk * 256;
    {
      size_t m = (size_t)b * 2048 + s0 + tid;
      gx[tid] = coords[m * 9 + 3];
      gy[tid] = coords[m * 9 + 4];
      gz[tid] = coords[m * 9 + 5];
    }
    if (tid < 64) {
      int which = tid >> 4, p = tid & 15;
      int j = h * 16 + p;
      float v = (which == 0) ? Wpq[j] : (which == 1) ? Wpq[128 + j]
               : (which == 2) ? Wpq[256 + j] : bpq[j];
      wco[which][p] = v;
    }
    __syncthreads();
#pragma unroll
    for (int iter = 0; iter < 2; iter++) {
      int task = tid + iter * 256;
      int p = task >> 5, c0 = (task & 31) * 8;
      float w0 = wco[0][p], w1 = wco[1][p], w2 = wco[2][p], bb = wco[3][p];
      short8 o;
#pragma unroll
      for (int i = 0; i < 8; i++) {
        int c = c0 + i;
        int sl = (c >> 6) * 64 + sinv64(c & 63);
        o[i] = bf16_of(gx[sl] * w0 + gy[sl] * w1 + gz[sl] * w2 + bb);
      }
      *reinterpret_cast<short8*>(&VaT[((size_t)bh * 48 + 32 + p) * S_ + s0 + c0]) = o;
    }
  }
}

// ---------------- QKV GEMM (M=4096, N=768, K=256), 64x64 tile (768 blocks, 3/CU) ----------------

__global__ __launch_bounds__(256) void qkv_gemm(
    const short* __restrict__ Xb, const short* __restrict__ Wt,
    const float* __restrict__ bq, const float* __restrict__ bk, const float* __restrict__ bv,
    short* __restrict__ Qa, short* __restrict__ Ka, short* __restrict__ VaT) {
  __shared__ __align__(16) short As[64 * 136];
  __shared__ __align__(16) short Bs[64 * 136];
  int m0 = blockIdx.x * 64, n0 = blockIdx.y * 64;
  int tid = threadIdx.x, lane = tid & 63, w = tid >> 6;
  int t = lane & 15, g = lane >> 4, kf = g * 8;
  int wr = (w >> 1) * 32, wc = (w & 1) * 32;
  f32x4 acc[2][2] = {};
  int srow = tid >> 2, skc = (tid & 3) * 32;
  for (int ph = 0; ph < 2; ph++) {
    int k0 = ph * 128;
    __syncthreads();
    {
      const uint4* xsrc = reinterpret_cast<const uint4*>(&Xb[(size_t)(m0 + srow) * 256 + k0 + skc]);
      const uint4* wsrc = reinterpret_cast<const uint4*>(&Wt[(size_t)(n0 + srow) * 256 + k0 + skc]);
#pragma unroll
      for (int i = 0; i < 4; i++)
        *reinterpret_cast<uint4*>(&As[srow * 136 + skc + i * 8]) = xsrc[i];
#pragma unroll
      for (int i = 0; i < 4; i++)
        *reinterpret_cast<uint4*>(&Bs[srow * 136 + skc + i * 8]) = wsrc[i];
    }
    __syncthreads();
#pragma unroll
    for (int kk = 0; kk < 4; kk++) {
      short8 a[2], bb[2];
#pragma unroll
      for (int i = 0; i < 2; i++)
        a[i] = *reinterpret_cast<const short8*>(&As[(wr + i * 16 + t) * 136 + kk * 32 + kf]);
#pragma unroll
      for (int jj = 0; jj < 2; jj++)
        bb[jj] = *reinterpret_cast<const short8*>(&Bs[(wc + jj * 16 + t) * 136 + kk * 32 + kf]);
#pragma unroll
      for (int i = 0; i < 2; i++)
#pragma unroll
        for (int jj = 0; jj < 2; jj++)
          acc[i][jj] = __builtin_amdgcn_mfma_f32_16x16x32_bf16(a[i], bb[jj], acc[i][jj], 0, 0, 0);
    }
  }
  __syncthreads();
  short* Cs = As;
  const float scale = 0.17677669529663687f * LOG2E;  // (1/sqrt(32)) * log2e
  int b = m0 >> 11, sbase = m0 & 2047;
#pragma unroll
  for (int i = 0; i < 2; i++)
#pragma unroll
    for (int jj = 0; jj < 2; jj++)
#pragma unroll
      for (int r = 0; r < 4; r++) {
        int rl = wr + i * 16 + g * 4 + r;
        int cl = wc + jj * 16 + t;
        int n = n0 + cl;
        float v = acc[i][jj][r];
        if (n < 256) v = (v + bq[n]) * scale;
        else if (n < 512) v = v + bk[n - 256];
        else v = v + bv[n - 512];
        Cs[rl * 72 + cl] = bf16_of(v);
      }
  __syncthreads();
  if (n0 < 512) {
#pragma unroll
    for (int i2 = 0; i2 < 2; i2++) {
      int task = tid + i2 * 256;
      int row = task >> 3, c = task & 7;
      int n = n0 + c * 8;
      short* dst = (n < 256) ? Qa : Ka;
      int nn = n & 255;
      int hh = nn >> 5, d = nn & 31;
      *reinterpret_cast<short8*>(&dst[((size_t)(b * 8 + hh) * S_ + sbase + row) * AUGQ + d]) =
          *reinterpret_cast<const short8*>(&Cs[row * 72 + c * 8]);
    }
  } else {
    int hv0 = (n0 - 512) >> 5;
#pragma unroll
    for (int i2 = 0; i2 < 2; i2++) {
      int task = tid + i2 * 256;
      int fl = task >> 3, s8 = task & 7;
      short8 o;
#pragma unroll
      for (int i = 0; i < 8; i++) o[i] = Cs[sinv64(s8 * 8 + i) * 72 + fl];
      int hh = hv0 + (fl >> 5), d = fl & 31;
      *reinterpret_cast<short8*>(&VaT[((size_t)(b * 8 + hh) * 48 + d) * S_ + sbase + s8 * 8]) = o;
    }
  }
}

// ---------------- flash attention: NSPLIT=8, K dbuf + V single-buffer, MFMA lsum ----------------
// grid 2048 (XCD-swizzled); LDS: K0 @0 (9216), K1 @9216, V @18432 (6912) = 25344.
// Epilogue overlays Of (128 x 52 f32 = 26624B). Block LDS = 26624B -> 6 blocks/CU LDS-wise.
// No min-waves bound: natural VGPR allocation (no spill by construction).

__global__ __launch_bounds__(256) void attn(
    const short* __restrict__ Qa, const short* __restrict__ Ka,
    const short* __restrict__ VaT,
    short* __restrict__ Ctx, float* __restrict__ AccL) {
  __shared__ __align__(16) char smem[26624];

  int bid = blockIdx.x;
  int xcd = bid & 7, slot = bid >> 3;       // slot 0..255
  int gidx = xcd * 16 + (slot >> 4);        // 0..127 = bhv*8+split
  int it = slot & 15;
  int split = gidx & 7;
  int bhv = gidx >> 3;

  int tid = threadIdx.x, lane = tid & 63, w = tid >> 6;
  int t = lane & 15, g = lane >> 4, kf = g * 8;
  int q0w = it * 128 + w * 32;
  size_t bh = (size_t)bhv * S_;

  short8 aq[2][2];
#pragma unroll
  for (int g2 = 0; g2 < 2; g2++)
#pragma unroll
    for (int c = 0; c < 2; c++)
      aq[g2][c] = *reinterpret_cast<const short8*>(
          &Qa[(bh + q0w + g2 * 16 + t) * AUGQ + c * 32 + kf]);

  short8 onesA = {};
  if (t == 0) {
#pragma unroll
    for (int i = 0; i < 8; i++) onesA[i] = 0x3F80;  // bf16(1.0)
  }

  f32x4 OaccA[3] = {}, OaccB[3] = {};
  f32x4 OaccA3 = {}, OaccB3 = {};

  uint4 kreg0, kreg1, vreg0, vreg1;
  int srow = tid >> 3, sko = (tid & 7) * 8;
  const int jt0 = split * NJ;

  auto issue = [&](int jt) {
    const uint4* ks = reinterpret_cast<const uint4*>(&Ka[(bh + jt * 64) * AUGQ]);
    kreg0 = ks[tid];
    kreg1 = ks[tid + 256];
    size_t vb = (size_t)bhv * 48 * S_ + jt * 64;
    vreg0 = *reinterpret_cast<const uint4*>(&VaT[vb + (size_t)srow * S_ + sko]);
    if (tid < 128)
      vreg1 = *reinterpret_cast<const uint4*>(&VaT[vb + (size_t)(srow + 32) * S_ + sko]);
  };
  auto commitK = [&](int buf) {
    short* Kd = (short*)(smem + buf * 9216);
    *reinterpret_cast<uint4*>(&Kd[srow * KPAD + sko]) = kreg0;
    *reinterpret_cast<uint4*>(&Kd[(srow + 32) * KPAD + sko]) = kreg1;
  };
  auto commitV = [&]() {
    short* Vd = (short*)(smem + 18432);
    *reinterpret_cast<uint4*>(&Vd[srow * KPAD + sko]) = vreg0;
    if (tid < 128)
      *reinterpret_cast<uint4*>(&Vd[(srow + 32) * KPAD + sko]) = vreg1;
  };

  issue(jt0);
  commitK(0);
  commitV();
  __syncthreads();

  for (int j = 0; j < NJ; j++) {
    int cur = j & 1;
    if (j + 1 < NJ) issue(jt0 + j + 1);
    const short* Kc = (const short*)(smem + cur * 9216);
    const short* Vc = (const short*)(smem + 18432);
    short8 pA[2], pB[2];
#pragma unroll
    for (int sub = 0; sub < 4; sub++) {
      short8 ka0 = *reinterpret_cast<const short8*>(&Kc[(sub * 16 + t) * KPAD + kf]);
      short8 ka1 = *reinterpret_cast<const short8*>(&Kc[(sub * 16 + t) * KPAD + 32 + kf]);
      f32x4 sA = {}, sB = {};
      sA = __builtin_amdgcn_mfma_f32_16x16x32_bf16(ka0, aq[0][0], sA, 0, 0, 0);
      sA = __builtin_amdgcn_mfma_f32_16x16x32_bf16(ka1, aq[0][1], sA, 0, 0, 0);
      sB = __builtin_amdgcn_mfma_f32_16x16x32_bf16(ka0, aq[1][0], sB, 0, 0, 0);
      sB = __builtin_amdgcn_mfma_f32_16x16x32_bf16(ka1, aq[1][1], sB, 0, 0, 0);
      float a0 = exp2f(sA[0]), a1 = exp2f(sA[1]), a2 = exp2f(sA[2]), a3 = exp2f(sA[3]);
      float b0 = exp2f(sB[0]), b1 = exp2f(sB[1]), b2 = exp2f(sB[2]), b3 = exp2f(sB[3]);
      int ww = sub & 1, off = (sub >> 1) * 4;
      pA[ww][off + 0] = bf16_of(a0); pA[ww][off + 1] = bf16_of(a1);
      pA[ww][off + 2] = bf16_of(a2); pA[ww][off + 3] = bf16_of(a3);
      pB[ww][off + 0] = bf16_of(b0); pB[ww][off + 1] = bf16_of(b1);
      pB[ww][off + 2] = bf16_of(b2); pB[ww][off + 3] = bf16_of(b3);
    }
    if (j + 1 < NJ) commitK(cur ^ 1);  // K is double-buffered: overlap with PV
    __builtin_amdgcn_s_setprio(1);
#pragma unroll
    for (int tt = 0; tt < 3; tt++) {
#pragma unroll
      for (int w2 = 0; w2 < 2; w2++) {
        short8 va = *reinterpret_cast<const short8*>(&Vc[(tt * 16 + t) * KPAD + w2 * 32 + kf]);
        OaccA[tt] = __builtin_amdgcn_mfma_f32_16x16x32_bf16(va, pA[w2], OaccA[tt], 0, 0, 0);
        OaccB[tt] = __builtin_amdgcn_mfma_f32_16x16x32_bf16(va, pB[w2], OaccB[tt], 0, 0, 0);
      }
    }
#pragma unroll
    for (int w2 = 0; w2 < 2; w2++) {
      OaccA3 = __builtin_amdgcn_mfma_f32_16x16x32_bf16(onesA, pA[w2], OaccA3, 0, 0, 0);
      OaccB3 = __builtin_amdgcn_mfma_f32_16x16x32_bf16(onesA, pB[w2], OaccB3, 0, 0, 0);
    }
    __builtin_amdgcn_s_setprio(0);
    __syncthreads();                       // all waves done reading V (and K[cur])
    if (j + 1 < NJ) {
      commitV();                           // write next V tile
      __syncthreads();
    }
  }

  float* Of = (float*)smem;
#pragma unroll
  for (int tt = 0; tt < 3; tt++)
#pragma unroll
    for (int r = 0; r < 4; r++) {
      Of[(w * 32 + t) * 52 + tt * 16 + g * 4 + r] = OaccA[tt][r];
      Of[(w * 32 + 16 + t) * 52 + tt * 16 + g * 4 + r] = OaccB[tt][r];
    }
  if (lane < 16) {
    size_t lb = (size_t)(split * NBH + bhv) * S_ + q0w + lane;
    AccL[lb] = OaccA3[0];
    AccL[lb + 16] = OaccB3[0];
  }
  __syncthreads();
  short* CtxP = Ctx + (size_t)split * NBH * S_ * 48;
  size_t obase = bh + it * 128;
  for (int task = tid; task < 768; task += 256) {
    int row = task / 6, c8 = task % 6;
    const float* src = &Of[row * 52 + c8 * 8];
    short8 o;
#pragma unroll
    for (int i = 0; i < 8; i++) o[i] = bf16_of(src[i]);
    *reinterpret_cast<short8*>(&CtxP[(obase + row) * 48 + c8 * 8]) = o;
  }
}

// ---------------- output projection + fused 8-way split-merge + fused point_proj ----------------

__global__ __launch_bounds__(512) void out_gemm(
    const short* __restrict__ Ctx, const float* __restrict__ AccL,
    const short* __restrict__ Wot, const float* __restrict__ bo,
    const float* __restrict__ Wpo, const float* __restrict__ bpo,
    float* __restrict__ Out) {
  const size_t CTXSZ = (size_t)NBH * S_ * 48;
  int m0 = blockIdx.x * 64;
  int tid = threadIdx.x;
  int b = m0 >> 11, sbase = m0 & 2047;

  if (blockIdx.y == 4) {
    int row = tid >> 3, hh = tid & 7;
    int m = m0 + row, s = sbase + row;
    size_t rowO = (size_t)(b * 8 + hh) * S_ + s;
    float l = 0.f;
#pragma unroll
    for (int sp = 0; sp < NSPLIT; sp++) l += AccL[(size_t)sp * NBH * S_ + rowO];
    float inv = 1.0f / l;
    float a0 = 0.f, a1 = 0.f, a2 = 0.f;
#pragma unroll
    for (int half = 0; half < 2; half++) {
      float sum[8] = {};
#pragma unroll
      for (int sp = 0; sp < NSPLIT; sp++) {
        short8 v = *reinterpret_cast<const short8*>(&Ctx[sp * CTXSZ + rowO * 48 + 32 + half * 8]);
#pragma unroll
        for (int c = 0; c < 8; c++) sum[c] += f_of_bf16(v[c]);
      }
#pragma unroll
      for (int c = 0; c < 8; c++) {
        float val = sum[c] * inv;
        int j = hh * 16 + half * 8 + c;
        a0 += val * Wpo[j * 3 + 0];
        a1 += val * Wpo[j * 3 + 1];
        a2 += val * Wpo[j * 3 + 2];
      }
    }
    a0 += __shfl_xor(a0, 1); a0 += __shfl_xor(a0, 2); a0 += __shfl_xor(a0, 4);
    a1 += __shfl_xor(a1, 1); a1 += __shfl_xor(a1, 2); a1 += __shfl_xor(a1, 4);
    a2 += __shfl_xor(a2, 1); a2 += __shfl_xor(a2, 2); a2 += __shfl_xor(a2, 4);
    if (hh == 0) {
      float* po = Out + (size_t)MTOT * 256;
      po[(size_t)m * 3 + 0] = a0 + bpo[0];
      po[(size_t)m * 3 + 1] = a1 + bpo[1];
      po[(size_t)m * 3 + 2] = a2 + bpo[2];
    }
    return;
  }

  __shared__ __align__(16) short As[64 * 136];
  __shared__ __align__(16) short Bs[64 * 136];
  int n0 = blockIdx.y * 64;
  int lane = tid & 63, w = tid >> 6;
  int t = lane & 15, g = lane >> 4, kf = g * 8;
  int wm = w & 3, wn = w >> 2;
  f32x4 acc[2] = {};
  int srow = tid >> 3, skc = (tid & 7) * 16;
  for (int ph = 0; ph < 2; ph++) {
    int k0 = ph * 128;
    __syncthreads();
    {
      int kg = k0 + skc;
      int hh = kg >> 5, d0 = kg & 31;
      size_t rowO = (size_t)(b * 8 + hh) * S_ + sbase + srow;
      float l = 0.f;
#pragma unroll
      for (int sp = 0; sp < NSPLIT; sp++) l += AccL[(size_t)sp * NBH * S_ + rowO];
      float inv = 1.0f / l;
#pragma unroll
      for (int half = 0; half < 2; half++) {
        float sum[8] = {};
#pragma unroll
        for (int sp = 0; sp < NSPLIT; sp++) {
          short8 a = *reinterpret_cast<const short8*>(&Ctx[sp * CTXSZ + rowO * 48 + d0 + half * 8]);
#pragma unroll
          for (int c = 0; c < 8; c++) sum[c] += f_of_bf16(a[c]);
        }
        short8 o;
#pragma unroll
        for (int c = 0; c < 8; c++) o[c] = bf16_of(sum[c] * inv);
        *reinterpret_cast<short8*>(&As[srow * 136 + skc + half * 8]) = o;
      }
      *reinterpret_cast<uint4*>(&Bs[srow * 136 + skc]) =
          *reinterpret_cast<const uint4*>(&Wot[(size_t)(n0 + srow) * 256 + kg]);
      *reinterpret_cast<uint4*>(&Bs[srow * 136 + skc + 8]) =
          *reinterpret_cast<const uint4*>(&Wot[(size_t)(n0 + srow) * 256 + kg + 8]);
    }
    __syncthreads();
#pragma unroll
    for (int kk = 0; kk < 4; kk++) {
      short8 a = *reinterpret_cast<const short8*>(&As[(wm * 16 + t) * 136 + kk * 32 + kf]);
#pragma unroll
      for (int jj = 0; jj < 2; jj++) {
        short8 bb = *reinterpret_cast<const short8*>(&Bs[(wn * 32 + jj * 16 + t) * 136 + kk * 32 + kf]);
        acc[jj] = __builtin_amdgcn_mfma_f32_16x16x32_bf16(a, bb, acc[jj], 0, 0, 0);
      }
    }
  }
#pragma unroll
  for (int jj = 0; jj < 2; jj++)
#pragma unroll
    for (int r = 0; r < 4; r++) {
      int mrow = m0 + wm * 16 + g * 4 + r;
      int n = n0 + wn * 32 + jj * 16 + t;
      Out[(size_t)mrow * 256 + n] = acc[jj][r] + bo[n];
    }
}

// ---------------- launch ----------------

extern "C" void kernel_launch(void* const* d_in, const int* in_sizes, int n_in,
                              void* d_out, int out_size, void* d_ws, size_t ws_size,
                              hipStream_t stream) {
  const float* seq    = (const float*)d_in[0];
  const float* coords = (const float*)d_in[1];
  const int*   mask   = (const int*)d_in[3];
  const float* Wq  = (const float*)d_in[4];
  const float* bq  = (const float*)d_in[5];
  const float* Wk  = (const float*)d_in[6];
  const float* bk  = (const float*)d_in[7];
  const float* Wv  = (const float*)d_in[8];
  const float* bv  = (const float*)d_in[9];
  const float* Wpq = (const float*)d_in[10];
  const float* bpq = (const float*)d_in[11];
  const float* Wpk = (const float*)d_in[12];
  const float* bpk = (const float*)d_in[13];
  const float* Wo  = (const float*)d_in[14];
  const float* bo  = (const float*)d_in[15];
  const float* Wpo = (const float*)d_in[16];
  const float* bpo = (const float*)d_in[17];
  float* out = (float*)d_out;

  char* ws = (char*)d_ws;
  short* Wqkv_t = (short*)ws; ws += 768 * 256 * 2;
  short* Wo_t   = (short*)ws; ws += 256 * 256 * 2;
  short* Xb     = (short*)ws; ws += (size_t)MTOT * D_ * 2;
  short* Qa     = (short*)ws; ws += (size_t)NBH * S_ * AUGQ * 2;
  short* Ka     = (short*)ws; ws += (size_t)NBH * S_ * AUGQ * 2;
  short* VaT    = (short*)ws; ws += (size_t)NBH * 48 * S_ * 2;
  short* Ctx    = (short*)ws; ws += (size_t)NSPLIT * NBH * S_ * 48 * 2;
  float* AccL   = (float*)ws; ws += (size_t)NSPLIT * NBH * S_ * 4;

  prep_all<<<832, 256, 0, stream>>>(Wq, Wk, Wv, Wo, seq, coords, mask,
                                    Wpq, bpq, Wpk, bpk,
                                    Wqkv_t, Wo_t, Xb, Qa, Ka, VaT);
  qkv_gemm<<<dim3(64, 12), 256, 0, stream>>>(Xb, Wqkv_t, bq, bk, bv, Qa, Ka, VaT);
  attn<<<2048, 256, 0, stream>>>(Qa, Ka, VaT, Ctx, AccL);
  out_gemm<<<dim3(64, 5), 512, 0, stream>>>(Ctx, AccL, Wo_t, bo, Wpo, bpo, out);
}

// Round 19
// 59.890 us; speedup vs baseline: 1.1377x; 1.1377x over previous
//
#include <hip/hip_runtime.h>
#include <hip/hip_bf16.h>

#define D_ 256
#define H_ 8
#define B_ 2
#define S_ 2048
#define MTOT 4096
#define AUGQ 64          // q(32) + pq(16) + [maskbias](1) + pad(15)
#define NBH 16           // B_*H_
#define KPAD 72
#define NSPLIT 4
#define NJ 8             // key tiles (of 64) per split
#define LOG2E 1.4426950408889634f

typedef __attribute__((ext_vector_type(8))) short short8;
typedef __attribute__((ext_vector_type(4))) short short4v;
typedef __attribute__((ext_vector_type(4))) float f32x4;

static __device__ __forceinline__ short bf16_of(float f) {
  union { __hip_bfloat16 h; short s; } u;
  u.h = __float2bfloat16(f);
  return u.s;
}
static __device__ __forceinline__ float f_of_bf16(short s) {
  union { float f; unsigned int u; } u;
  u.u = ((unsigned int)(unsigned short)s) << 16;
  return u.f;
}

// key permutation within a 64-key tile: V column c holds key sinv(c)
static __device__ __forceinline__ int sinv64(int c) {
  return (((((c >> 2) & 1) << 1) | ((c >> 5) & 1)) << 4) + (((c >> 3) & 3) << 2) + (c & 3);
}

// ---------------- prep: sectioned by blockIdx ----------------

__global__ __launch_bounds__(256) void prep_all(
    const float* __restrict__ Wq, const float* __restrict__ Wk,
    const float* __restrict__ Wv, const float* __restrict__ Wo,
    const float* __restrict__ X, const float* __restrict__ coords,
    const int* __restrict__ mask,
    const float* __restrict__ Wpq, const float* __restrict__ bpq,
    const float* __restrict__ Wpk, const float* __restrict__ bpk,
    short* __restrict__ Wqkv_t, short* __restrict__ Wo_t,
    short* __restrict__ Xb,
    short* __restrict__ Qa, short* __restrict__ Ka, short* __restrict__ VaT) {
  int bid = blockIdx.x, tid = threadIdx.x;

  if (bid < 64) {
    __shared__ short T[64][72];
    const float* src;
    short* dst;
    int k0, n0g;
    if (bid < 48) {
      int nt = bid >> 2;
      k0 = (bid & 3) * 64;
      n0g = nt * 64;
      src = (n0g < 256) ? Wq : (n0g < 512 ? Wk : Wv);
      dst = Wqkv_t;
    } else {
      int t2 = bid - 48;
      k0 = (t2 & 3) * 64;
      n0g = (t2 >> 2) * 64;
      src = Wo;
      dst = Wo_t;
    }
    int ncol = n0g & 255;
    int rr = tid >> 4, cc = (tid & 15) * 4;
#pragma unroll
    for (int i = 0; i < 4; i++) {
      int r = rr + i * 16;
      f32x4 v = *reinterpret_cast<const f32x4*>(&src[(size_t)(k0 + r) * 256 + ncol + cc]);
      T[cc + 0][r] = bf16_of(v[0]);
      T[cc + 1][r] = bf16_of(v[1]);
      T[cc + 2][r] = bf16_of(v[2]);
      T[cc + 3][r] = bf16_of(v[3]);
    }
    __syncthreads();
    int n = tid >> 2, kk = (tid & 3) * 16;
    *reinterpret_cast<short8*>(&dst[(size_t)(n0g + n) * 256 + k0 + kk]) =
        *reinterpret_cast<const short8*>(&T[n][kk]);
    *reinterpret_cast<short8*>(&dst[(size_t)(n0g + n) * 256 + k0 + kk + 8]) =
        *reinterpret_cast<const short8*>(&T[n][kk + 8]);
    return;
  }

  if (bid < 576) {
    size_t i = (size_t)(bid - 64) * 2048 + tid * 8;
    f32x4 v0 = *reinterpret_cast<const f32x4*>(&X[i]);
    f32x4 v1 = *reinterpret_cast<const f32x4*>(&X[i + 4]);
    short8 o;
    o[0] = bf16_of(v0[0]); o[1] = bf16_of(v0[1]); o[2] = bf16_of(v0[2]); o[3] = bf16_of(v0[3]);
    o[4] = bf16_of(v1[0]); o[5] = bf16_of(v1[1]); o[6] = bf16_of(v1[2]); o[7] = bf16_of(v1[3]);
    *reinterpret_cast<short8*>(&Xb[i]) = o;
    return;
  }

  if (bid < 704) {
    int idx = (bid - 576) * 256 + tid;
    int m = idx >> 3, h = idx & 7;
    int b = m >> 11, s = m & 2047;
    float r0 = coords[m * 9 + 3], r1 = coords[m * 9 + 4], r2 = coords[m * 9 + 5];
    size_t base = ((size_t)(b * 8 + h) * S_ + s) * AUGQ;
    short8 pqv[2], pkv[2];
#pragma unroll
    for (int c = 0; c < 2; c++)
#pragma unroll
      for (int i = 0; i < 8; i++) {
        int j = h * 16 + c * 8 + i;
        float pq = r0 * Wpq[j] + r1 * Wpq[128 + j] + r2 * Wpq[256 + j] + bpq[j];
        float pk = r0 * Wpk[j] + r1 * Wpk[128 + j] + r2 * Wpk[256 + j] + bpk[j];
        pqv[c][i] = bf16_of(pq * LOG2E);
        pkv[c][i] = bf16_of(pk * 0.25f);
      }
    short8 padq = {};
    padq[0] = bf16_of(LOG2E);
    short8 padk = {};
    padk[0] = mask[m] ? (short)0 : bf16_of(-1e9f);
    short8 z = {};
    *reinterpret_cast<short8*>(&Qa[base + 32]) = pqv[0];
    *reinterpret_cast<short8*>(&Qa[base + 40]) = pqv[1];
    *reinterpret_cast<short8*>(&Qa[base + 48]) = padq;
    *reinterpret_cast<short8*>(&Qa[base + 56]) = z;
    *reinterpret_cast<short8*>(&Ka[base + 32]) = pkv[0];
    *reinterpret_cast<short8*>(&Ka[base + 40]) = pkv[1];
    *reinterpret_cast<short8*>(&Ka[base + 48]) = padk;
    *reinterpret_cast<short8*>(&Ka[base + 56]) = z;
    return;
  }

  {
    int idx = (bid - 704) * 256 + tid;
    int s8 = idx & 255, p = (idx >> 8) & 15, bh = idx >> 12;
    int b = bh >> 3, h = bh & 7, j = h * 16 + p;
    float w0 = Wpq[j], w1 = Wpq[128 + j], w2 = Wpq[256 + j], bb = bpq[j];
    short8 o;
#pragma unroll
    for (int i = 0; i < 8; i++) {
      int c = (s8 & 7) * 8 + i;
      int m = b * 2048 + (s8 >> 3) * 64 + sinv64(c);
      o[i] = bf16_of(coords[m * 9 + 3] * w0 + coords[m * 9 + 4] * w1 +
                     coords[m * 9 + 5] * w2 + bb);
    }
    *reinterpret_cast<short8*>(&VaT[((size_t)bh * 48 + 32 + p) * S_ + s8 * 8]) = o;
  }
}

// ---------------- QKV GEMM (M=4096, N=768, K=256), 64x64 tile (768 blocks, 3/CU) ----------------

__global__ __launch_bounds__(256) void qkv_gemm(
    const short* __restrict__ Xb, const short* __restrict__ Wt,
    const float* __restrict__ bq, const float* __restrict__ bk, const float* __restrict__ bv,
    short* __restrict__ Qa, short* __restrict__ Ka, short* __restrict__ VaT) {
  __shared__ __align__(16) short As[64 * 136];
  __shared__ __align__(16) short Bs[64 * 136];
  int m0 = blockIdx.x * 64, n0 = blockIdx.y * 64;
  int tid = threadIdx.x, lane = tid & 63, w = tid >> 6;
  int t = lane & 15, g = lane >> 4, kf = g * 8;
  int wr = (w >> 1) * 32, wc = (w & 1) * 32;
  f32x4 acc[2][2] = {};
  int srow = tid >> 2, skc = (tid & 3) * 32;
  for (int ph = 0; ph < 2; ph++) {
    int k0 = ph * 128;
    __syncthreads();
    {
      const uint4* xsrc = reinterpret_cast<const uint4*>(&Xb[(size_t)(m0 + srow) * 256 + k0 + skc]);
      const uint4* wsrc = reinterpret_cast<const uint4*>(&Wt[(size_t)(n0 + srow) * 256 + k0 + skc]);
#pragma unroll
      for (int i = 0; i < 4; i++)
        *reinterpret_cast<uint4*>(&As[srow * 136 + skc + i * 8]) = xsrc[i];
#pragma unroll
      for (int i = 0; i < 4; i++)
        *reinterpret_cast<uint4*>(&Bs[srow * 136 + skc + i * 8]) = wsrc[i];
    }
    __syncthreads();
#pragma unroll
    for (int kk = 0; kk < 4; kk++) {
      short8 a[2], bb[2];
#pragma unroll
      for (int i = 0; i < 2; i++)
        a[i] = *reinterpret_cast<const short8*>(&As[(wr + i * 16 + t) * 136 + kk * 32 + kf]);
#pragma unroll
      for (int jj = 0; jj < 2; jj++)
        bb[jj] = *reinterpret_cast<const short8*>(&Bs[(wc + jj * 16 + t) * 136 + kk * 32 + kf]);
#pragma unroll
      for (int i = 0; i < 2; i++)
#pragma unroll
        for (int jj = 0; jj < 2; jj++)
          acc[i][jj] = __builtin_amdgcn_mfma_f32_16x16x32_bf16(a[i], bb[jj], acc[i][jj], 0, 0, 0);
    }
  }
  __syncthreads();
  short* Cs = As;
  const float scale = 0.17677669529663687f * LOG2E;  // (1/sqrt(32)) * log2e
  int b = m0 >> 11, sbase = m0 & 2047;
#pragma unroll
  for (int i = 0; i < 2; i++)
#pragma unroll
    for (int jj = 0; jj < 2; jj++)
#pragma unroll
      for (int r = 0; r < 4; r++) {
        int rl = wr + i * 16 + g * 4 + r;
        int cl = wc + jj * 16 + t;
        int n = n0 + cl;
        float v = acc[i][jj][r];
        if (n < 256) v = (v + bq[n]) * scale;
        else if (n < 512) v = v + bk[n - 256];
        else v = v + bv[n - 512];
        Cs[rl * 72 + cl] = bf16_of(v);
      }
  __syncthreads();
  if (n0 < 512) {
#pragma unroll
    for (int i2 = 0; i2 < 2; i2++) {
      int task = tid + i2 * 256;
      int row = task >> 3, c = task & 7;
      int n = n0 + c * 8;
      short* dst = (n < 256) ? Qa : Ka;
      int nn = n & 255;
      int hh = nn >> 5, d = nn & 31;
      *reinterpret_cast<short8*>(&dst[((size_t)(b * 8 + hh) * S_ + sbase + row) * AUGQ + d]) =
          *reinterpret_cast<const short8*>(&Cs[row * 72 + c * 8]);
    }
  } else {
    int hv0 = (n0 - 512) >> 5;
#pragma unroll
    for (int i2 = 0; i2 < 2; i2++) {
      int task = tid + i2 * 256;
      int fl = task >> 3, s8 = task & 7;
      short8 o;
#pragma unroll
      for (int i = 0; i < 8; i++) o[i] = Cs[sinv64(s8 * 8 + i) * 72 + fl];
      int hh = hv0 + (fl >> 5), d = fl & 31;
      *reinterpret_cast<short8*>(&VaT[((size_t)(b * 8 + hh) * 48 + d) * S_ + sbase + s8 * 8]) = o;
    }
  }
}

// ---------------- flash attention: swapped QK^T, register P, K=32 PV, MFMA lsum ----------------

__global__ __launch_bounds__(256, 4) void attn(
    const short* __restrict__ Qa, const short* __restrict__ Ka,
    const short* __restrict__ VaT,
    short* __restrict__ Ctx, float* __restrict__ AccL) {
  __shared__ __align__(16) char smem[32256];

  int bid = blockIdx.x;
  int xcd = bid & 7, slot = bid >> 3;
  int gidx = xcd * 8 + (slot >> 4);
  int it = slot & 15;
  int split = gidx & 3;
  int bhv = gidx >> 2;

  int tid = threadIdx.x, lane = tid & 63, w = tid >> 6;
  int t = lane & 15, g = lane >> 4, kf = g * 8;
  int q0w = it * 128 + w * 32;
  size_t bh = (size_t)bhv * S_;

  short8 aq[2][2];
#pragma unroll
  for (int g2 = 0; g2 < 2; g2++)
#pragma unroll
    for (int c = 0; c < 2; c++)
      aq[g2][c] = *reinterpret_cast<const short8*>(
          &Qa[(bh + q0w + g2 * 16 + t) * AUGQ + c * 32 + kf]);

  // ones A-fragment: row 0 (of the virtual lsum tile) = 1.0, rows 1-15 = 0
  short8 onesA = {};
  if (t == 0) {
#pragma unroll
    for (int i = 0; i < 8; i++) onesA[i] = 0x3F80;  // bf16(1.0)
  }

  f32x4 OaccA[3] = {}, OaccB[3] = {};
  f32x4 OaccA3 = {}, OaccB3 = {};

  uint4 kreg0, kreg1, vreg0, vreg1;
  int srow = tid >> 3, sko = (tid & 7) * 8;
  const int jt0 = split * NJ;

  auto issue = [&](int jt) {
    const uint4* ks = reinterpret_cast<const uint4*>(&Ka[(bh + jt * 64) * AUGQ]);
    kreg0 = ks[tid];
    kreg1 = ks[tid + 256];
    size_t vb = (size_t)bhv * 48 * S_ + jt * 64;
    vreg0 = *reinterpret_cast<const uint4*>(&VaT[vb + (size_t)srow * S_ + sko]);
    if (tid < 128)
      vreg1 = *reinterpret_cast<const uint4*>(&VaT[vb + (size_t)(srow + 32) * S_ + sko]);
  };
  auto commit = [&](int buf) {
    short* Kd = (short*)(smem + buf * 9216);
    short* Vd = (short*)(smem + 18432 + buf * 6912);
    *reinterpret_cast<uint4*>(&Kd[srow * KPAD + sko]) = kreg0;
    *reinterpret_cast<uint4*>(&Kd[(srow + 32) * KPAD + sko]) = kreg1;
    *reinterpret_cast<uint4*>(&Vd[srow * KPAD + sko]) = vreg0;
    if (tid < 128)
      *reinterpret_cast<uint4*>(&Vd[(srow + 32) * KPAD + sko]) = vreg1;
  };

  issue(jt0);
  commit(0);
  __syncthreads();

  for (int j = 0; j < NJ; j++) {
    int cur = j & 1;
    if (j + 1 < NJ) issue(jt0 + j + 1);
    const short* Kc = (const short*)(smem + cur * 9216);
    const short* Vc = (const short*)(smem + 18432 + cur * 6912);
    short8 pA[2], pB[2];
#pragma unroll
    for (int sub = 0; sub < 4; sub++) {
      short8 ka0 = *reinterpret_cast<const short8*>(&Kc[(sub * 16 + t) * KPAD + kf]);
      short8 ka1 = *reinterpret_cast<const short8*>(&Kc[(sub * 16 + t) * KPAD + 32 + kf]);
      f32x4 sA = {}, sB = {};
      sA = __builtin_amdgcn_mfma_f32_16x16x32_bf16(ka0, aq[0][0], sA, 0, 0, 0);
      sA = __builtin_amdgcn_mfma_f32_16x16x32_bf16(ka1, aq[0][1], sA, 0, 0, 0);
      sB = __builtin_amdgcn_mfma_f32_16x16x32_bf16(ka0, aq[1][0], sB, 0, 0, 0);
      sB = __builtin_amdgcn_mfma_f32_16x16x32_bf16(ka1, aq[1][1], sB, 0, 0, 0);
      float a0 = exp2f(sA[0]), a1 = exp2f(sA[1]), a2 = exp2f(sA[2]), a3 = exp2f(sA[3]);
      float b0 = exp2f(sB[0]), b1 = exp2f(sB[1]), b2 = exp2f(sB[2]), b3 = exp2f(sB[3]);
      int ww = sub & 1, off = (sub >> 1) * 4;
      pA[ww][off + 0] = bf16_of(a0); pA[ww][off + 1] = bf16_of(a1);
      pA[ww][off + 2] = bf16_of(a2); pA[ww][off + 3] = bf16_of(a3);
      pB[ww][off + 0] = bf16_of(b0); pB[ww][off + 1] = bf16_of(b1);
      pB[ww][off + 2] = bf16_of(b2); pB[ww][off + 3] = bf16_of(b3);
    }
    // prefetch commit BEFORE PV: LDS writes to buf cur^1 overlap the MFMA cluster
    if (j + 1 < NJ) commit(cur ^ 1);
    __builtin_amdgcn_s_setprio(1);
#pragma unroll
    for (int tt = 0; tt < 3; tt++) {
#pragma unroll
      for (int w2 = 0; w2 < 2; w2++) {
        short8 va = *reinterpret_cast<const short8*>(&Vc[(tt * 16 + t) * KPAD + w2 * 32 + kf]);
        OaccA[tt] = __builtin_amdgcn_mfma_f32_16x16x32_bf16(va, pA[w2], OaccA[tt], 0, 0, 0);
        OaccB[tt] = __builtin_amdgcn_mfma_f32_16x16x32_bf16(va, pB[w2], OaccB[tt], 0, 0, 0);
      }
    }
    // lsum tile: D[0][q] += sum_k P[k][q] on the matrix pipe
#pragma unroll
    for (int w2 = 0; w2 < 2; w2++) {
      OaccA3 = __builtin_amdgcn_mfma_f32_16x16x32_bf16(onesA, pA[w2], OaccA3, 0, 0, 0);
      OaccB3 = __builtin_amdgcn_mfma_f32_16x16x32_bf16(onesA, pB[w2], OaccB3, 0, 0, 0);
    }
    __builtin_amdgcn_s_setprio(0);
    __syncthreads();
  }

  float* Of = (float*)smem;
#pragma unroll
  for (int tt = 0; tt < 3; tt++)
#pragma unroll
    for (int r = 0; r < 4; r++) {
      Of[(w * 32 + t) * 52 + tt * 16 + g * 4 + r] = OaccA[tt][r];
      Of[(w * 32 + 16 + t) * 52 + tt * 16 + g * 4 + r] = OaccB[tt][r];
    }
  if (lane < 16) {
    size_t lb = (size_t)(split * NBH + bhv) * S_ + q0w + lane;
    AccL[lb] = OaccA3[0];
    AccL[lb + 16] = OaccB3[0];
  }
  __syncthreads();
  short* CtxP = Ctx + (size_t)split * NBH * S_ * 48;
  size_t obase = bh + it * 128;
  for (int task = tid; task < 768; task += 256) {
    int row = task / 6, c8 = task % 6;
    const float* src = &Of[row * 52 + c8 * 8];
    short8 o;
#pragma unroll
    for (int i = 0; i < 8; i++) o[i] = bf16_of(src[i]);
    *reinterpret_cast<short8*>(&CtxP[(obase + row) * 48 + c8 * 8]) = o;
  }
}

// ---------------- output projection + fused 4-way split-merge + fused point_proj ----------------

__global__ __launch_bounds__(512) void out_gemm(
    const short* __restrict__ Ctx, const float* __restrict__ AccL,
    const short* __restrict__ Wot, const float* __restrict__ bo,
    const float* __restrict__ Wpo, const float* __restrict__ bpo,
    float* __restrict__ Out) {
  const size_t CTXSZ = (size_t)NBH * S_ * 48;
  int m0 = blockIdx.x * 64;
  int tid = threadIdx.x;
  int b = m0 >> 11, sbase = m0 & 2047;

  if (blockIdx.y == 4) {
    int row = tid >> 3, hh = tid & 7;
    int m = m0 + row, s = sbase + row;
    size_t rowO = (size_t)(b * 8 + hh) * S_ + s;
    float l = 0.f;
#pragma unroll
    for (int sp = 0; sp < NSPLIT; sp++) l += AccL[(size_t)sp * NBH * S_ + rowO];
    float inv = 1.0f / l;
    float a0 = 0.f, a1 = 0.f, a2 = 0.f;
#pragma unroll
    for (int half = 0; half < 2; half++) {
      float sum[8] = {};
#pragma unroll
      for (int sp = 0; sp < NSPLIT; sp++) {
        short8 v = *reinterpret_cast<const short8*>(&Ctx[sp * CTXSZ + rowO * 48 + 32 + half * 8]);
#pragma unroll
        for (int c = 0; c < 8; c++) sum[c] += f_of_bf16(v[c]);
      }
#pragma unroll
      for (int c = 0; c < 8; c++) {
        float val = sum[c] * inv;
        int j = hh * 16 + half * 8 + c;
        a0 += val * Wpo[j * 3 + 0];
        a1 += val * Wpo[j * 3 + 1];
        a2 += val * Wpo[j * 3 + 2];
      }
    }
    a0 += __shfl_xor(a0, 1); a0 += __shfl_xor(a0, 2); a0 += __shfl_xor(a0, 4);
    a1 += __shfl_xor(a1, 1); a1 += __shfl_xor(a1, 2); a1 += __shfl_xor(a1, 4);
    a2 += __shfl_xor(a2, 1); a2 += __shfl_xor(a2, 2); a2 += __shfl_xor(a2, 4);
    if (hh == 0) {
      float* po = Out + (size_t)MTOT * 256;
      po[(size_t)m * 3 + 0] = a0 + bpo[0];
      po[(size_t)m * 3 + 1] = a1 + bpo[1];
      po[(size_t)m * 3 + 2] = a2 + bpo[2];
    }
    return;
  }

  __shared__ __align__(16) short As[64 * 136];
  __shared__ __align__(16) short Bs[64 * 136];
  int n0 = blockIdx.y * 64;
  int lane = tid & 63, w = tid >> 6;
  int t = lane & 15, g = lane >> 4, kf = g * 8;
  int wm = w & 3, wn = w >> 2;
  f32x4 acc[2] = {};
  int srow = tid >> 3, skc = (tid & 7) * 16;
  for (int ph = 0; ph < 2; ph++) {
    int k0 = ph * 128;
    __syncthreads();
    {
      int kg = k0 + skc;
      int hh = kg >> 5, d0 = kg & 31;
      size_t rowO = (size_t)(b * 8 + hh) * S_ + sbase + srow;
      float l = 0.f;
#pragma unroll
      for (int sp = 0; sp < NSPLIT; sp++) l += AccL[(size_t)sp * NBH * S_ + rowO];
      float inv = 1.0f / l;
#pragma unroll
      for (int half = 0; half < 2; half++) {
        float sum[8] = {};
#pragma unroll
        for (int sp = 0; sp < NSPLIT; sp++) {
          short8 a = *reinterpret_cast<const short8*>(&Ctx[sp * CTXSZ + rowO * 48 + d0 + half * 8]);
#pragma unroll
          for (int c = 0; c < 8; c++) sum[c] += f_of_bf16(a[c]);
        }
        short8 o;
#pragma unroll
        for (int c = 0; c < 8; c++) o[c] = bf16_of(sum[c] * inv);
        *reinterpret_cast<short8*>(&As[srow * 136 + skc + half * 8]) = o;
      }
      *reinterpret_cast<uint4*>(&Bs[srow * 136 + skc]) =
          *reinterpret_cast<const uint4*>(&Wot[(size_t)(n0 + srow) * 256 + kg]);
      *reinterpret_cast<uint4*>(&Bs[srow * 136 + skc + 8]) =
          *reinterpret_cast<const uint4*>(&Wot[(size_t)(n0 + srow) * 256 + kg + 8]);
    }
    __syncthreads();
#pragma unroll
    for (int kk = 0; kk < 4; kk++) {
      short8 a = *reinterpret_cast<const short8*>(&As[(wm * 16 + t) * 136 + kk * 32 + kf]);
#pragma unroll
      for (int jj = 0; jj < 2; jj++) {
        short8 bb = *reinterpret_cast<const short8*>(&Bs[(wn * 32 + jj * 16 + t) * 136 + kk * 32 + kf]);
        acc[jj] = __builtin_amdgcn_mfma_f32_16x16x32_bf16(a, bb, acc[jj], 0, 0, 0);
      }
    }
  }
#pragma unroll
  for (int jj = 0; jj < 2; jj++)
#pragma unroll
    for (int r = 0; r < 4; r++) {
      int mrow = m0 + wm * 16 + g * 4 + r;
      int n = n0 + wn * 32 + jj * 16 + t;
      Out[(size_t)mrow * 256 + n] = acc[jj][r] + bo[n];
    }
}

// ---------------- launch ----------------

extern "C" void kernel_launch(void* const* d_in, const int* in_sizes, int n_in,
                              void* d_out, int out_size, void* d_ws, size_t ws_size,
                              hipStream_t stream) {
  const float* seq    = (const float*)d_in[0];
  const float* coords = (const float*)d_in[1];
  const int*   mask   = (const int*)d_in[3];
  const float* Wq  = (const float*)d_in[4];
  const float* bq  = (const float*)d_in[5];
  const float* Wk  = (const float*)d_in[6];
  const float* bk  = (const float*)d_in[7];
  const float* Wv  = (const float*)d_in[8];
  const float* bv  = (const float*)d_in[9];
  const float* Wpq = (const float*)d_in[10];
  const float* bpq = (const float*)d_in[11];
  const float* Wpk = (const float*)d_in[12];
  const float* bpk = (const float*)d_in[13];
  const float* Wo  = (const float*)d_in[14];
  const float* bo  = (const float*)d_in[15];
  const float* Wpo = (const float*)d_in[16];
  const float* bpo = (const float*)d_in[17];
  float* out = (float*)d_out;

  char* ws = (char*)d_ws;
  short* Wqkv_t = (short*)ws; ws += 768 * 256 * 2;
  short* Wo_t   = (short*)ws; ws += 256 * 256 * 2;
  short* Xb     = (short*)ws; ws += (size_t)MTOT * D_ * 2;
  short* Qa     = (short*)ws; ws += (size_t)NBH * S_ * AUGQ * 2;
  short* Ka     = (short*)ws; ws += (size_t)NBH * S_ * AUGQ * 2;
  short* VaT    = (short*)ws; ws += (size_t)NBH * 48 * S_ * 2;
  short* Ctx    = (short*)ws; ws += (size_t)NSPLIT * NBH * S_ * 48 * 2;
  float* AccL   = (float*)ws; ws += (size_t)NSPLIT * NBH * S_ * 4;

  prep_all<<<960, 256, 0, stream>>>(Wq, Wk, Wv, Wo, seq, coords, mask,
                                    Wpq, bpq, Wpk, bpk,
                                    Wqkv_t, Wo_t, Xb, Qa, Ka, VaT);
  qkv_gemm<<<dim3(64, 12), 256, 0, stream>>>(Xb, Wqkv_t, bq, bk, bv, Qa, Ka, VaT);
  attn<<<1024, 256, 0, stream>>>(Qa, Ka, VaT, Ctx, AccL);
  out_gemm<<<dim3(64, 5), 512, 0, stream>>>(Ctx, AccL, Wo_t, bo, Wpo, bpo, out);
}